// Round 9
// baseline (106.358 us; speedup 1.0000x reference)
//
#include <hip/hip_runtime.h>
#include <math.h>

#define B_ 4
#define C_ 64
#define D_ 32
#define H_ 64
#define W_ 64
#define S_ (D_*H_*W_)      // 131072 spatial per (b,c)
#define S4_ (S_/4)         // 32768

typedef float floatx4 __attribute__((ext_vector_type(4)));

// ---------------- Kernel 1: channel-wise max & mean -> xc[B][2][D][H][W] ----
__global__ __launch_bounds__(256) void reduce_kernel(const float* __restrict__ x,
                                                     float* __restrict__ xc) {
    int i  = blockIdx.x * 256 + threadIdx.x;          // float4 index over B*S/4
    int b  = i >> 15;                                  // i / S4_
    int s4 = i & (S4_ - 1);
    const float4* x4 = reinterpret_cast<const float4*>(x) + (size_t)b * C_ * S4_ + s4;
    float4 v = x4[0];
    float mx0 = v.x, mx1 = v.y, mx2 = v.z, mx3 = v.w;
    float sm0 = v.x, sm1 = v.y, sm2 = v.z, sm3 = v.w;
    #pragma unroll 8
    for (int c = 1; c < C_; ++c) {
        float4 t = x4[(size_t)c * S4_];
        mx0 = fmaxf(mx0, t.x); sm0 += t.x;
        mx1 = fmaxf(mx1, t.y); sm1 += t.y;
        mx2 = fmaxf(mx2, t.z); sm2 += t.z;
        mx3 = fmaxf(mx3, t.w); sm3 += t.w;
    }
    float4* o = reinterpret_cast<float4*>(xc);
    float4 a; a.x = mx0; a.y = mx1; a.z = mx2; a.w = mx3;
    o[((size_t)b * 2 + 0) * S4_ + s4] = a;
    const float inv = 1.0f / 64.0f;
    float4 m; m.x = sm0 * inv; m.y = sm1 * inv; m.z = sm2 * inv; m.w = sm3 * inv;
    o[((size_t)b * 2 + 1) * S4_ + s4] = m;
}

// ------- Kernel 2 (fused): conv3d(2->1,k7,p3) + sigmoid + out = x*scale -----
// Tile: 64(W full rows) x 8(H) x 2(D) per 128-thread block -> 512 blocks
// (2/CU avg, 4 waves/CU; 32.3 KB LDS lets up to 4 reside as retirement skews).
// Thread: 4 W x 1 H x 2 D outputs. The two D outputs share every window read:
// plane z feeds dout d0 with kz=z and dout d0+1 with kz=z-1 (weights slide one
// plane in registers). 5 LDS reads per 56 FMAs -- half of round 6's rate.
// Halo per channel: 8(z) x 14(y) x 70(x), row stride 72.
#define YS 72
#define ZS (14*YS)         // 1008: z-plane stride
__global__ __launch_bounds__(128) void conv_gate_kernel(const float* __restrict__ xc,
                                                        const float* __restrict__ x,
                                                        const float* __restrict__ cw,
                                                        const float* __restrict__ cb,
                                                        float* __restrict__ out) {
    __shared__ float tile[8 * ZS];      // 8064 floats = 32.3 KB
    __shared__ float wl[784];           // both channels' weights, 8-padded rows

    const int tid = threadIdx.x;
    const int b  = blockIdx.z >> 4;            // 16 d-slabs per batch
    const int d0 = (blockIdx.z & 15) * 2;
    const int h0 = blockIdx.y * 8;

    const int w4 = tid & 15;           // w = 4*w4 (16 lanes cover a full W-row)
    const int hh = tid >> 4;           // h = h0 + hh (0..7)

    // weights, both channels: wl[ch][kz][ky][8], 8th lane zero
    for (int idx = tid; idx < 784; idx += 128) {
        int ch = idx / 392;
        int r  = idx - ch * 392;
        int kz = r / 56;
        int r2 = r - kz * 56;
        int ky = r2 >> 3;
        int kw = r2 & 7;
        wl[idx] = (kw < 7) ? cw[ch * 343 + kz * 49 + ky * 7 + kw] : 0.f;
    }

    float acc0[4] = {0.f, 0.f, 0.f, 0.f};   // dout = d0
    float acc1[4] = {0.f, 0.f, 0.f, 0.f};   // dout = d0+1
    for (int ch = 0; ch < 2; ++ch) {
        // halo for this channel: logical 8 x 14 x 70
        for (int idx = tid; idx < 8 * 14 * 70; idx += 128) {
            int z  = idx / 980;
            int r  = idx - z * 980;
            int y  = r / 70;
            int xw = r - y * 70;
            int gd = d0 + z - 3, gh = h0 + y - 3, gw = xw - 3;
            float v = 0.f;
            if ((unsigned)gd < (unsigned)D_ && (unsigned)gh < (unsigned)H_ &&
                (unsigned)gw < (unsigned)W_)
                v = xc[((size_t)(b * 2 + ch)) * S_ + gd * (H_ * W_) + gh * W_ + gw];
            tile[z * ZS + y * YS + xw] = v;
        }
        __syncthreads();   // halo (and, first pass, weights) visible

        const float* wch = &wl[ch * 392];
        for (int ky = 0; ky < 7; ++ky) {
            const float* trow = &tile[(hh + ky) * YS + w4 * 4];
            const float* wrow = wch + ky * 8;
            float wp[7] = {0.f, 0.f, 0.f, 0.f, 0.f, 0.f, 0.f};
            for (int z = 0; z < 8; ++z) {
                const float* rp = trow + z * ZS;
                float4 f0 = *reinterpret_cast<const float4*>(rp);
                float4 f1 = *reinterpret_cast<const float4*>(rp + 4);
                float2 f2 = *reinterpret_cast<const float2*>(rp + 8);
                float win[10] = {f0.x, f0.y, f0.z, f0.w,
                                 f1.x, f1.y, f1.z, f1.w, f2.x, f2.y};
                float wc[7];
                if (z < 7) {                    // dout d0: kz = z
                    float4 wa = *reinterpret_cast<const float4*>(wrow + z * 56);
                    float4 wb = *reinterpret_cast<const float4*>(wrow + z * 56 + 4);
                    wc[0] = wa.x; wc[1] = wa.y; wc[2] = wa.z; wc[3] = wa.w;
                    wc[4] = wb.x; wc[5] = wb.y; wc[6] = wb.z;
                    #pragma unroll
                    for (int kw = 0; kw < 7; ++kw) {
                        acc0[0] = fmaf(win[kw + 0], wc[kw], acc0[0]);
                        acc0[1] = fmaf(win[kw + 1], wc[kw], acc0[1]);
                        acc0[2] = fmaf(win[kw + 2], wc[kw], acc0[2]);
                        acc0[3] = fmaf(win[kw + 3], wc[kw], acc0[3]);
                    }
                }
                if (z >= 1) {                   // dout d0+1: kz = z-1 (slid)
                    #pragma unroll
                    for (int kw = 0; kw < 7; ++kw) {
                        acc1[0] = fmaf(win[kw + 0], wp[kw], acc1[0]);
                        acc1[1] = fmaf(win[kw + 1], wp[kw], acc1[1]);
                        acc1[2] = fmaf(win[kw + 2], wp[kw], acc1[2]);
                        acc1[3] = fmaf(win[kw + 3], wp[kw], acc1[3]);
                    }
                }
                if (z < 7) {
                    #pragma unroll
                    for (int k = 0; k < 7; ++k) wp[k] = wc[k];
                }
            }
        }
        __syncthreads();   // before next channel's fill overwrites the tile
    }

    // ---- sigmoid in registers ----
    const float bias = cb[0];
    floatx4 s0, s1;
    s0.x = 1.0f / (1.0f + __expf(-(acc0[0] + bias)));
    s0.y = 1.0f / (1.0f + __expf(-(acc0[1] + bias)));
    s0.z = 1.0f / (1.0f + __expf(-(acc0[2] + bias)));
    s0.w = 1.0f / (1.0f + __expf(-(acc0[3] + bias)));
    s1.x = 1.0f / (1.0f + __expf(-(acc1[0] + bias)));
    s1.y = 1.0f / (1.0f + __expf(-(acc1[1] + bias)));
    s1.z = 1.0f / (1.0f + __expf(-(acc1[2] + bias)));
    s1.w = 1.0f / (1.0f + __expf(-(acc1[3] + bias)));

    // ---- apply gate to all 64 channels at this thread's 2 float4s ----
    // wave = 4 adjacent H-rows x full W at each of 2 D-planes: 1KB spans.
    const int h = h0 + hh, w = w4 * 4;
    const size_t sp = (size_t)d0 * (H_ * W_) + (size_t)h * W_ + w;
    const float* xp = x + (size_t)b * C_ * S_ + sp;
    float* op = out + (size_t)b * C_ * S_ + sp;
    #pragma unroll 8
    for (int c = 0; c < C_; ++c) {
        const size_t off = (size_t)c * S_;
        floatx4 xv0 = *reinterpret_cast<const floatx4*>(xp + off);
        floatx4 xv1 = *reinterpret_cast<const floatx4*>(xp + off + H_ * W_);
        *reinterpret_cast<floatx4*>(op + off) = xv0 * s0;
        *reinterpret_cast<floatx4*>(op + off + H_ * W_) = xv1 * s1;
    }
}

extern "C" void kernel_launch(void* const* d_in, const int* in_sizes, int n_in,
                              void* d_out, int out_size, void* d_ws, size_t ws_size,
                              hipStream_t stream) {
    const float* x  = (const float*)d_in[0];
    const float* cw = (const float*)d_in[1];   // [1][2][7][7][7]
    const float* cb = (const float*)d_in[2];   // [1]
    float* out = (float*)d_out;
    float* xc  = (float*)d_ws;                 // B*2*S floats (4 MiB)

    reduce_kernel<<<dim3((B_ * S4_) / 256), dim3(256), 0, stream>>>(x, xc);
    conv_gate_kernel<<<dim3(1, H_ / 8, B_ * (D_ / 2)), dim3(128), 0, stream>>>(
        xc, x, cw, cb, out);
}

// Round 10
// 90.065 us; speedup vs baseline: 1.1809x; 1.1809x over previous
//
#include <hip/hip_runtime.h>
#include <math.h>

#define B_ 4
#define C_ 64
#define D_ 32
#define H_ 64
#define W_ 64
#define S_ (D_*H_*W_)      // 131072 spatial per (b,c)
#define S4_ (S_/4)         // 32768
#define HW_ (H_*W_)        // 4096

typedef float floatx4 __attribute__((ext_vector_type(4)));

// ---------------- Kernel 1: channel-wise max & mean -> xc[B][2][D][H][W] ----
__global__ __launch_bounds__(256) void reduce_kernel(const float* __restrict__ x,
                                                     float* __restrict__ xc) {
    int i  = blockIdx.x * 256 + threadIdx.x;          // float4 index over B*S/4
    int b  = i >> 15;                                  // i / S4_
    int s4 = i & (S4_ - 1);
    const float4* x4 = reinterpret_cast<const float4*>(x) + (size_t)b * C_ * S4_ + s4;
    float4 v = x4[0];
    float mx0 = v.x, mx1 = v.y, mx2 = v.z, mx3 = v.w;
    float sm0 = v.x, sm1 = v.y, sm2 = v.z, sm3 = v.w;
    #pragma unroll 8
    for (int c = 1; c < C_; ++c) {
        float4 t = x4[(size_t)c * S4_];
        mx0 = fmaxf(mx0, t.x); sm0 += t.x;
        mx1 = fmaxf(mx1, t.y); sm1 += t.y;
        mx2 = fmaxf(mx2, t.z); sm2 += t.z;
        mx3 = fmaxf(mx3, t.w); sm3 += t.w;
    }
    float4* o = reinterpret_cast<float4*>(xc);
    float4 a; a.x = mx0; a.y = mx1; a.z = mx2; a.w = mx3;
    o[((size_t)b * 2 + 0) * S4_ + s4] = a;
    const float inv = 1.0f / 64.0f;
    float4 m; m.x = sm0 * inv; m.y = sm1 * inv; m.z = sm2 * inv; m.w = sm3 * inv;
    o[((size_t)b * 2 + 1) * S4_ + s4] = m;
}

// ------- Kernel 2 (fused): conv3d(2->1,k7,p3) + sigmoid + out = x*scale -----
// 256 blocks (1/CU) x 256 threads. Tile: 64W x 8H x 4D = 2048 outputs,
// 8/thread (float4 of W, 1 H, 2 adjacent D via kz-sharing: plane z feeds
// dout dbase with kz=z and dout dbase+1 with kz=z-1, weights slid in regs).
// Halo: both channels resident: 2 x 10z x 14y x 70x, row stride 72 (16B-
// aligned rows). Register-staged fill: 8 independent global loads in flight.
// One __syncthreads() total.
#define TZ 10
#define TY 14
#define TXS 72
#define PLANE (TY*TXS)      // 1008
#define CHSZ (TZ*PLANE)     // 10080 floats per channel
#define HALO_N (2*TZ*TY*70) // 19600 logical fill elements

__global__ __launch_bounds__(256, 1) void conv_gate_kernel(const float* __restrict__ xc,
                                                           const float* __restrict__ x,
                                                           const float* __restrict__ cw,
                                                           const float* __restrict__ cb,
                                                           float* __restrict__ out) {
    __shared__ __align__(16) float tile[2 * CHSZ];   // 80.64 KB
    __shared__ __align__(16) float wl[784];          // both ch, [kz][ky][8] 0-padded

    const int tid = threadIdx.x;
    const int b  = blockIdx.z >> 3;
    const int d0 = (blockIdx.z & 7) * 4;
    const int h0 = blockIdx.y * 8;

    const int w4 = tid & 15;            // w = 4*w4
    const int hh = (tid >> 4) & 7;      // h = h0 + hh
    const int dd = tid >> 7;            // 0..1
    const int dbase = d0 + 2 * dd;      // this thread's 2 output d-planes

    // weights: wl[ch][kz][ky][8] (latency hides under halo staging)
    for (int idx = tid; idx < 784; idx += 256) {
        int ch = idx / 392;
        int r  = idx - ch * 392;
        int kz = r / 56;
        int r2 = r - kz * 56;
        int ky = r2 >> 3;
        int kw = r2 & 7;
        wl[idx] = (kw < 7) ? cw[ch * 343 + kz * 49 + ky * 7 + kw] : 0.f;
    }

    // halo fill, register-staged: 8 independent loads in flight per thread
    for (int base = tid; base < HALO_N; base += 256 * 8) {
        float sv[8];
        int   sa[8];
        #pragma unroll
        for (int k = 0; k < 8; ++k) {
            int idx = base + k * 256;
            sv[k] = 0.f;
            sa[k] = -1;
            if (idx < HALO_N) {
                int ch = idx / 9800;            // TZ*TY*70
                int r  = idx - ch * 9800;
                int z  = r / 980;               // TY*70
                int r2 = r - z * 980;
                int y  = r2 / 70;
                int xw = r2 - y * 70;
                sa[k] = ch * CHSZ + z * PLANE + y * TXS + xw;
                int gd = d0 + z - 3, gh = h0 + y - 3, gw = xw - 3;
                if ((unsigned)gd < (unsigned)D_ && (unsigned)gh < (unsigned)H_ &&
                    (unsigned)gw < (unsigned)W_)
                    sv[k] = xc[(size_t)(b * 2 + ch) * S_ + gd * HW_ + gh * W_ + gw];
            }
        }
        #pragma unroll
        for (int k = 0; k < 8; ++k)
            if (sa[k] >= 0) tile[sa[k]] = sv[k];
    }
    __syncthreads();

    // ---- conv: 2 D-outputs share every window read ----
    float acc0[4] = {0.f, 0.f, 0.f, 0.f};   // dout = dbase     (kz = z)
    float acc1[4] = {0.f, 0.f, 0.f, 0.f};   // dout = dbase + 1 (kz = z-1)
    for (int ch = 0; ch < 2; ++ch) {
        const float* tch = &tile[ch * CHSZ + 2 * dd * PLANE + w4 * 4];
        const float* wch = &wl[ch * 392];
        for (int ky = 0; ky < 7; ++ky) {
            const float* trow = tch + (hh + ky) * TXS;
            const float* wrow = wch + ky * 8;
            float wp[7];
            #pragma unroll
            for (int z = 0; z < 8; ++z) {
                const float* rp = trow + z * PLANE;
                float4 f0 = *reinterpret_cast<const float4*>(rp);
                float4 f1 = *reinterpret_cast<const float4*>(rp + 4);
                float2 f2 = *reinterpret_cast<const float2*>(rp + 8);
                float win[10] = {f0.x, f0.y, f0.z, f0.w,
                                 f1.x, f1.y, f1.z, f1.w, f2.x, f2.y};
                if (z >= 1) {                   // dbase+1 uses previous plane's w
                    #pragma unroll
                    for (int kw = 0; kw < 7; ++kw) {
                        acc1[0] = fmaf(win[kw + 0], wp[kw], acc1[0]);
                        acc1[1] = fmaf(win[kw + 1], wp[kw], acc1[1]);
                        acc1[2] = fmaf(win[kw + 2], wp[kw], acc1[2]);
                        acc1[3] = fmaf(win[kw + 3], wp[kw], acc1[3]);
                    }
                }
                if (z < 7) {
                    float4 wa = *reinterpret_cast<const float4*>(wrow + z * 56);
                    float4 wb = *reinterpret_cast<const float4*>(wrow + z * 56 + 4);
                    float wc[7] = {wa.x, wa.y, wa.z, wa.w, wb.x, wb.y, wb.z};
                    #pragma unroll
                    for (int kw = 0; kw < 7; ++kw) {
                        acc0[0] = fmaf(win[kw + 0], wc[kw], acc0[0]);
                        acc0[1] = fmaf(win[kw + 1], wc[kw], acc0[1]);
                        acc0[2] = fmaf(win[kw + 2], wc[kw], acc0[2]);
                        acc0[3] = fmaf(win[kw + 3], wc[kw], acc0[3]);
                    }
                    #pragma unroll
                    for (int k = 0; k < 7; ++k) wp[k] = wc[k];
                }
            }
        }
    }

    // ---- sigmoid in registers ----
    const float bias = cb[0];
    floatx4 s0, s1;
    s0.x = 1.0f / (1.0f + __expf(-(acc0[0] + bias)));
    s0.y = 1.0f / (1.0f + __expf(-(acc0[1] + bias)));
    s0.z = 1.0f / (1.0f + __expf(-(acc0[2] + bias)));
    s0.w = 1.0f / (1.0f + __expf(-(acc0[3] + bias)));
    s1.x = 1.0f / (1.0f + __expf(-(acc1[0] + bias)));
    s1.y = 1.0f / (1.0f + __expf(-(acc1[1] + bias)));
    s1.z = 1.0f / (1.0f + __expf(-(acc1[2] + bias)));
    s1.w = 1.0f / (1.0f + __expf(-(acc1[3] + bias)));

    // ---- gating stream: 64 channels x 2 d-planes per thread ----
    // wave = 4 adjacent H-rows x full W at fixed d: contiguous 1KB spans.
    // Batch 16 loads then 16 stores: 16KB in flight per wave.
    const int h = h0 + hh, w = w4 * 4;
    const size_t sp = (size_t)dbase * HW_ + (size_t)h * W_ + w;
    const float* xp = x + (size_t)b * C_ * S_ + sp;
    float* op = out + (size_t)b * C_ * S_ + sp;
    for (int c = 0; c < C_; c += 8) {
        floatx4 v[16];
        #pragma unroll
        for (int k = 0; k < 8; ++k) {
            const size_t off = (size_t)(c + k) * S_;
            v[2 * k]     = *reinterpret_cast<const floatx4*>(xp + off);
            v[2 * k + 1] = *reinterpret_cast<const floatx4*>(xp + off + HW_);
        }
        #pragma unroll
        for (int k = 0; k < 8; ++k) {
            const size_t off = (size_t)(c + k) * S_;
            *reinterpret_cast<floatx4*>(op + off)       = v[2 * k] * s0;
            *reinterpret_cast<floatx4*>(op + off + HW_) = v[2 * k + 1] * s1;
        }
    }
}

extern "C" void kernel_launch(void* const* d_in, const int* in_sizes, int n_in,
                              void* d_out, int out_size, void* d_ws, size_t ws_size,
                              hipStream_t stream) {
    const float* x  = (const float*)d_in[0];
    const float* cw = (const float*)d_in[1];   // [1][2][7][7][7]
    const float* cb = (const float*)d_in[2];   // [1]
    float* out = (float*)d_out;
    float* xc  = (float*)d_ws;                 // B*2*S floats (4 MiB)

    reduce_kernel<<<dim3((B_ * S4_) / 256), dim3(256), 0, stream>>>(x, xc);
    conv_gate_kernel<<<dim3(1, H_ / 8, B_ * (D_ / 4)), dim3(256), 0, stream>>>(
        xc, x, cw, cb, out);
}